// Round 5
// baseline (1040.437 us; speedup 1.0000x reference)
//
#include <hip/hip_runtime.h>

#define IN_CH 128
#define HID   256

typedef __attribute__((ext_vector_type(8))) short bf16x8;
typedef __attribute__((ext_vector_type(4))) float f32x4;
typedef __attribute__((ext_vector_type(8))) unsigned short ushort8;

__device__ __forceinline__ ushort f2b(float f) {
    unsigned u = __float_as_uint(f);
    unsigned r = (u + 0x7fffu + ((u >> 16) & 1u)) >> 16;
    return (ushort)r;
}
__device__ __forceinline__ float b2f(ushort h) {
    return __uint_as_float(((unsigned)h) << 16);
}

// ================= fused counting-sort infrastructure =================
// count = [countD(N) | countA(N)] contiguous
__global__ void hist2_kernel(const int* __restrict__ dst, const int* __restrict__ edges,
                             int* __restrict__ count, int N, int E, int E2) {
    int e = blockIdx.x * 256 + threadIdx.x;
    if (e < E)  atomicAdd(&count[dst[e]], 1);
    if (e < E2) atomicAdd(&count[N + edges[(size_t)e * 2]], 1);
}

__global__ void scan1_kernel(const int* __restrict__ count, int* __restrict__ offs,
                             int* __restrict__ bsums, int M) {
    __shared__ int s[256];
    int t = threadIdx.x;
    int i = blockIdx.x * 256 + t;
    int v = (i < M) ? count[i] : 0;
    s[t] = v;
    __syncthreads();
    for (int d = 1; d < 256; d <<= 1) {
        int u = (t >= d) ? s[t - d] : 0;
        __syncthreads();
        s[t] += u;
        __syncthreads();
    }
    if (i < M) offs[i] = s[t] - v;
    if (t == 255) bsums[blockIdx.x] = s[255];
}

__global__ void scan2_kernel(int* __restrict__ bsums, int NB) {   // NB <= 1024
    __shared__ int s[1024];
    int t = threadIdx.x;
    int v = (t < NB) ? bsums[t] : 0;
    s[t] = v;
    __syncthreads();
    for (int d = 1; d < 1024; d <<= 1) {
        int u = (t >= d) ? s[t - d] : 0;
        __syncthreads();
        s[t] += u;
        __syncthreads();
    }
    if (t < NB) bsums[t] = s[t] - v;
}

__global__ void scan3_kernel(int* __restrict__ offs, const int* __restrict__ bsums,
                             int* __restrict__ cursor, int M) {
    int i = blockIdx.x * 256 + threadIdx.x;
    if (i < M) {
        int o = offs[i] + bsums[i >> 8];
        offs[i] = o;
        cursor[i] = o;
    }
}

// fused scatter: nbr (graph by dst) + pairs (candidates by a)
__global__ void build2_kernel(const int* __restrict__ src, const int* __restrict__ dst,
                              const int* __restrict__ edges, int* __restrict__ cursor,
                              int* __restrict__ nbr, unsigned long long* __restrict__ pairs,
                              int N, int E, int E2) {
    int e = blockIdx.x * 256 + threadIdx.x;
    if (e < E) {
        int d = dst[e];
        nbr[atomicAdd(&cursor[d], 1)] = src[e];
    }
    if (e < E2) {
        int a = edges[(size_t)e * 2 + 0];
        int b = edges[(size_t)e * 2 + 1];
        int pos = atomicAdd(&cursor[N + a], 1) - E;   // pairs prefix starts after E graph edges
        pairs[pos] = ((unsigned long long)(unsigned)b << 32) | (unsigned)e;
    }
}

// ================= bf16 conversions =================
__global__ void cvt_kernel(const float* __restrict__ in, ushort* __restrict__ o, int n4) {
    int i = blockIdx.x * 256 + threadIdx.x;
    if (i < n4) {
        float4 v = ((const float4*)in)[i];
        ushort4 u;
        u.x = f2b(v.x); u.y = f2b(v.y); u.z = f2b(v.z); u.w = f2b(v.w);
        ((ushort4*)o)[i] = u;
    }
}

// Wt[n][k] bf16 from Wl/Wr (n-major, k contiguous).
// PERM_K: the A-matrix channels were stored with P(c)=(c&~63)|((c&15)*4+((c>>4)&3)),
// so B's k-row at stored position k must use logical c = Pinv(k&63)+ (k&~63),
// Pinv(j) = (j&3)*16 + (j>>2).
template<bool PERM_K>
__global__ void prep_w_kernel(const float* __restrict__ Wl, const float* __restrict__ Wr,
                              ushort* __restrict__ Wt, int KH) {
    int ktot = 2 * KH;
    int idx = blockIdx.x * 256 + threadIdx.x;
    if (idx >= 256 * ktot) return;
    int n = idx / ktot, k = idx % ktot;
    int kh = (k < KH) ? k : (k - KH);
    int c = kh;
    if (PERM_K) {
        int j = kh & 63;
        c = (kh & ~63) | ((j & 3) * 16 + (j >> 2));
    }
    float v = (k < KH) ? Wl[(size_t)c * 256 + n] : Wr[(size_t)c * 256 + n];
    Wt[idx] = f2b(v);
}

// ================= gather-mean aggregation =================
__global__ void agg1_kernel(const ushort* __restrict__ xb, const int* __restrict__ nbr,
                            const int* __restrict__ offs, const int* __restrict__ count,
                            ushort* __restrict__ agg, int N) {
    int w = blockIdx.x * 4 + (threadIdx.x >> 6);
    if (w >= N) return;
    int lane = threadIdx.x & 63;
    int grp = lane >> 4, gl = lane & 15;
    int start = offs[w], cnt = count[w];
    float acc[8];
#pragma unroll
    for (int i = 0; i < 8; i++) acc[i] = 0.0f;
    for (int j = grp; j < cnt; j += 4) {
        int s = nbr[start + j];
        ushort8 v = *(const ushort8*)(xb + (size_t)s * IN_CH + gl * 8);
#pragma unroll
        for (int i = 0; i < 8; i++) acc[i] += b2f(v[i]);
    }
#pragma unroll
    for (int i = 0; i < 8; i++) acc[i] += __shfl_xor(acc[i], 16, 64);
#pragma unroll
    for (int i = 0; i < 8; i++) acc[i] += __shfl_xor(acc[i], 32, 64);
    if (grp == 0) {
        float r = 1.0f / fmaxf((float)cnt, 1.0f);
        ushort8 o;
#pragma unroll
        for (int i = 0; i < 8; i++) o[i] = f2b(acc[i] * r);
        *(ushort8*)(agg + (size_t)w * IN_CH + gl * 8) = o;
    }
}

__global__ void agg2_kernel(const ushort* __restrict__ h, const int* __restrict__ nbr,
                            const int* __restrict__ offs, const int* __restrict__ count,
                            ushort* __restrict__ agg, int N) {
    int w = blockIdx.x * 4 + (threadIdx.x >> 6);
    if (w >= N) return;
    int lane = threadIdx.x & 63;
    int half = lane >> 5, hl = lane & 31;
    int start = offs[w], cnt = count[w];
    float a0[8], a1[8];
#pragma unroll
    for (int i = 0; i < 8; i++) { a0[i] = 0.0f; a1[i] = 0.0f; }
    int j = half;
    for (; j + 2 < cnt; j += 4) {
        int s0 = nbr[start + j];
        int s1 = nbr[start + j + 2];
        ushort8 v0 = *(const ushort8*)(h + (size_t)s0 * HID + hl * 8);
        ushort8 v1 = *(const ushort8*)(h + (size_t)s1 * HID + hl * 8);
#pragma unroll
        for (int i = 0; i < 8; i++) { a0[i] += b2f(v0[i]); a1[i] += b2f(v1[i]); }
    }
    if (j < cnt) {
        int s0 = nbr[start + j];
        ushort8 v0 = *(const ushort8*)(h + (size_t)s0 * HID + hl * 8);
#pragma unroll
        for (int i = 0; i < 8; i++) a0[i] += b2f(v0[i]);
    }
#pragma unroll
    for (int i = 0; i < 8; i++) {
        a0[i] += a1[i];
        a0[i] += __shfl_xor(a0[i], 32, 64);
    }
    if (half == 0) {
        float r = 1.0f / fmaxf((float)cnt, 1.0f);
        ushort8 o;
#pragma unroll
        for (int i = 0; i < 8; i++) o[i] = f2b(a0[i] * r);
        *(ushort8*)(agg + (size_t)w * HID + hl * 8) = o;
    }
}

// ================= MFMA GEMM, permuted coalesced epilogue =================
// Output col c stored at P(c) = (c&~63) | ((c&15)*4 + ((c>>4)&3)).
// Lane's 4 nt-values become one contiguous ushort4 (8B) store.
template<int KTOT, bool RELU>
__global__ __launch_bounds__(256, 2)
void sage_gemm_mfma(const ushort* __restrict__ Aleft, const ushort* __restrict__ Aright,
                    const ushort* __restrict__ Wt, const float* __restrict__ bias,
                    ushort* __restrict__ out, int N) {
    constexpr int KH = KTOT / 2;
    constexpr int LDA = 40;
    __shared__ ushort As[64][LDA];
    __shared__ ushort Bs[256][LDA];

    const int t = threadIdx.x;
    const int wave = t >> 6;
    const int lane = t & 63;
    const int quad = lane >> 4;
    const int l16  = lane & 15;
    const int rowBase = blockIdx.x * 64;

    const int sRow = t >> 2;
    const int sChk = (t & 3) << 3;
    const bool aRowOK = (rowBase + sRow) < N;

    f32x4 acc[4][4];
#pragma unroll
    for (int i = 0; i < 4; i++)
#pragma unroll
        for (int j = 0; j < 4; j++) acc[i][j] = (f32x4)0.0f;

    for (int k0 = 0; k0 < KTOT; k0 += 32) {
        ulonglong2 a16 = {0ull, 0ull};
        if (aRowOK) {
            const ushort* Ap = (k0 < KH)
                ? (Aleft  + (size_t)(rowBase + sRow) * KH + (k0 + sChk))
                : (Aright + (size_t)(rowBase + sRow) * KH + (k0 - KH + sChk));
            a16 = *(const ulonglong2*)Ap;
        }
        ulonglong2 b16[4];
#pragma unroll
        for (int i = 0; i < 4; i++) {
            int n = sRow + i * 64;
            b16[i] = *(const ulonglong2*)(Wt + (size_t)n * KTOT + k0 + sChk);
        }

        __syncthreads();
        *(ulonglong2*)&As[sRow][sChk] = a16;
#pragma unroll
        for (int i = 0; i < 4; i++)
            *(ulonglong2*)&Bs[sRow + i * 64][sChk] = b16[i];
        __syncthreads();

        bf16x8 af[4], bf[4];
#pragma unroll
        for (int mt = 0; mt < 4; mt++)
            af[mt] = *(const bf16x8*)&As[mt * 16 + l16][quad * 8];
#pragma unroll
        for (int nt = 0; nt < 4; nt++)
            bf[nt] = *(const bf16x8*)&Bs[wave * 64 + nt * 16 + l16][quad * 8];
#pragma unroll
        for (int mt = 0; mt < 4; mt++)
#pragma unroll
            for (int nt = 0; nt < 4; nt++)
                acc[mt][nt] = __builtin_amdgcn_mfma_f32_16x16x32_bf16(
                    af[mt], bf[nt], acc[mt][nt], 0, 0, 0);
    }

    float bv[4];
#pragma unroll
    for (int nt = 0; nt < 4; nt++) bv[nt] = bias[wave * 64 + nt * 16 + l16]; // logical col
#pragma unroll
    for (int mt = 0; mt < 4; mt++) {
#pragma unroll
        for (int reg = 0; reg < 4; reg++) {
            int row = rowBase + mt * 16 + quad * 4 + reg;
            if (row < N) {
                ushort4 o;
                {
                    float v0 = acc[mt][0][reg] + bv[0];
                    float v1 = acc[mt][1][reg] + bv[1];
                    float v2 = acc[mt][2][reg] + bv[2];
                    float v3 = acc[mt][3][reg] + bv[3];
                    if (RELU) {
                        v0 = fmaxf(v0, 0.0f); v1 = fmaxf(v1, 0.0f);
                        v2 = fmaxf(v2, 0.0f); v3 = fmaxf(v3, 0.0f);
                    }
                    o.x = f2b(v0); o.y = f2b(v1); o.z = f2b(v2); o.w = f2b(v3);
                }
                // permuted store: cols {nt*16+l16} -> positions wave*64 + l16*4 + nt
                *(ushort4*)(out + (size_t)row * 256 + wave * 64 + l16 * 4) = o;
            }
        }
    }
}

// ================= decode: one wave per a-node over a-sorted pairs =================
// offsA/countA live at offs[N..2N); positions are offset by E.
__global__ void decode2_kernel(const ushort* __restrict__ z,
                               const unsigned long long* __restrict__ pairs,
                               const int* __restrict__ offsA, const int* __restrict__ countA,
                               float* __restrict__ out, int N, int baseE) {
    int a = blockIdx.x * 4 + (threadIdx.x >> 6);
    if (a >= N) return;
    int cnt = countA[a];
    if (cnt == 0) return;
    int lane = threadIdx.x & 63;
    int half = lane >> 5, hl = lane & 31;
    int start = offsA[a] - baseE;

    float ar[8];
    {
        ushort8 va = *(const ushort8*)(z + (size_t)a * HID + hl * 8);
#pragma unroll
        for (int i = 0; i < 8; i++) ar[i] = b2f(va[i]);
    }

    int j = half;
    for (; j + 2 < cnt; j += 4) {
        unsigned long long p0 = pairs[start + j];
        unsigned long long p1 = pairs[start + j + 2];
        int b0 = (int)(p0 >> 32), e0 = (int)(p0 & 0xffffffffu);
        int b1 = (int)(p1 >> 32), e1 = (int)(p1 & 0xffffffffu);
        ushort8 v0 = *(const ushort8*)(z + (size_t)b0 * HID + hl * 8);
        ushort8 v1 = *(const ushort8*)(z + (size_t)b1 * HID + hl * 8);
        float s0 = 0.f, s1 = 0.f;
#pragma unroll
        for (int i = 0; i < 8; i++) { s0 = fmaf(ar[i], b2f(v0[i]), s0);
                                      s1 = fmaf(ar[i], b2f(v1[i]), s1); }
#pragma unroll
        for (int off = 1; off < 32; off <<= 1) { s0 += __shfl_xor(s0, off, 64);
                                                 s1 += __shfl_xor(s1, off, 64); }
        if (hl == 0) { out[e0] = s0; out[e1] = s1; }
    }
    if (j < cnt) {
        unsigned long long p0 = pairs[start + j];
        int b0 = (int)(p0 >> 32), e0 = (int)(p0 & 0xffffffffu);
        ushort8 v0 = *(const ushort8*)(z + (size_t)b0 * HID + hl * 8);
        float s0 = 0.f;
#pragma unroll
        for (int i = 0; i < 8; i++) s0 = fmaf(ar[i], b2f(v0[i]), s0);
#pragma unroll
        for (int off = 1; off < 32; off <<= 1) s0 += __shfl_xor(s0, off, 64);
        if (hl == 0) out[e0] = s0;
    }
}

extern "C" void kernel_launch(void* const* d_in, const int* in_sizes, int n_in,
                              void* d_out, int out_size, void* d_ws, size_t ws_size,
                              hipStream_t stream) {
    const float* x    = (const float*)d_in[0];
    const int* eidx   = (const int*)d_in[1];
    const int* edges  = (const int*)d_in[2];
    const float* W1l  = (const float*)d_in[3];
    const float* b1   = (const float*)d_in[4];
    const float* W1r  = (const float*)d_in[5];
    const float* W2l  = (const float*)d_in[6];
    const float* b2   = (const float*)d_in[7];
    const float* W2r  = (const float*)d_in[8];
    float* out = (float*)d_out;

    const int N  = in_sizes[0] / IN_CH;
    const int E  = in_sizes[1] / 2;
    const int E2 = in_sizes[2] / 2;
    const int* src = eidx;
    const int* dst = eidx + E;
    const int M  = 2 * N;                      // fused sort domain
    const int NB = (M + 255) / 256;            // <= 1024

    // ws: ints count[2N] offs[2N] cursor[2N] bsums[1024] nbr[E] | pairs[E2] u64 | shorts...
    int* count  = (int*)d_ws;
    int* offs   = count + M;
    int* cursor = offs + M;
    int* bsums  = cursor + M;
    int* nbr    = bsums + 1024;
    size_t intWords = (size_t)3 * M + 1024 + E;
    intWords = (intWords + 1) & ~(size_t)1;
    unsigned long long* pairs = (unsigned long long*)((int*)d_ws + intWords);
    ushort* xb    = (ushort*)(pairs + E2);
    ushort* agg1b = xb + (size_t)N * IN_CH;
    ushort* agg2b = xb;                        // overlay after gemm1
    ushort* h     = agg1b + (size_t)N * IN_CH;
    ushort* z     = h + (size_t)N * HID;
    ushort* Wt1   = z + (size_t)N * HID;
    ushort* Wt2   = Wt1 + 256 * 256;

    // ---- conversions ----
    cvt_kernel<<<((N * IN_CH / 4) + 255) / 256, 256, 0, stream>>>(x, xb, N * IN_CH / 4);
    prep_w_kernel<false><<<(256 * 256 + 255) / 256, 256, 0, stream>>>(W1l, W1r, Wt1, IN_CH);
    prep_w_kernel<true><<<(256 * 512 + 255) / 256, 256, 0, stream>>>(W2l, W2r, Wt2, HID);

    // ---- fused counting sorts: graph by dst (count[0..N)) + pairs by a (count[N..2N)) ----
    hipMemsetAsync(count, 0, (size_t)M * sizeof(int), stream);
    {
        int Emax = (E > E2) ? E : E2;
        hist2_kernel<<<(Emax + 255) / 256, 256, 0, stream>>>(dst, edges, count, N, E, E2);
        scan1_kernel<<<NB, 256, 0, stream>>>(count, offs, bsums, M);
        scan2_kernel<<<1, 1024, 0, stream>>>(bsums, NB);
        scan3_kernel<<<NB, 256, 0, stream>>>(offs, bsums, cursor, M);
        build2_kernel<<<(Emax + 255) / 256, 256, 0, stream>>>(
            src, dst, edges, cursor, nbr, pairs, N, E, E2);
    }

    // ---- layer 1: h = relu([agg1b | xb] @ Wt1 + b1)  (h stored in P layout) ----
    agg1_kernel<<<(N + 3) / 4, 256, 0, stream>>>(xb, nbr, offs, count, agg1b, N);
    sage_gemm_mfma<2 * IN_CH, true><<<(N + 63) / 64, 256, 0, stream>>>(
        agg1b, xb, Wt1, b1, h, N);

    // ---- layer 2: z = [agg2b | h] @ Wt2 + b2  (P-layout in, Wt2 k-permuted; z in P layout) ----
    agg2_kernel<<<(N + 3) / 4, 256, 0, stream>>>(h, nbr, offs, count, agg2b, N);
    sage_gemm_mfma<2 * HID, false><<<(N + 63) / 64, 256, 0, stream>>>(
        agg2b, h, Wt2, b2, z, N);

    // ---- decode (dot product is invariant under shared P layout) ----
    decode2_kernel<<<(N + 3) / 4, 256, 0, stream>>>(z, pairs, offs + N, count + N, out, N, E);
}